// Round 10
// baseline (393.626 us; speedup 1.0000x reference)
//
#include <hip/hip_runtime.h>
#include <stdint.h>

typedef __bf16 bf16;
typedef __attribute__((ext_vector_type(8))) __bf16 bf16x8;
typedef __attribute__((ext_vector_type(4))) __bf16 bf16x4;
typedef __attribute__((ext_vector_type(2))) __bf16 bf16x2;
typedef __attribute__((ext_vector_type(4))) float f32x4;

#define GLOBAL_AS __attribute__((address_space(1)))
#define LDS_AS __attribute__((address_space(3)))

static __device__ __forceinline__ bf16 f2bf(float f) {
  unsigned u = __builtin_bit_cast(unsigned, f);
  u += 0x7fffu + ((u >> 16) & 1u);
  unsigned short h = (unsigned short)(u >> 16);
  return __builtin_bit_cast(bf16, h);
}

static __device__ __forceinline__ float waveSum(float v) {
  #pragma unroll
  for (int o = 32; o > 0; o >>= 1) v += __shfl_xor(v, o);
  return v;
}
static __device__ __forceinline__ float waveMax(float v) {
  #pragma unroll
  for (int o = 32; o > 0; o >>= 1) v = fmaxf(v, __shfl_xor(v, o));
  return v;
}

// BK=32 LDS swizzle (R6-proven: 0 bank conflicts, 3 blocks/CU)
static __device__ __forceinline__ int swz(int r, int c) { return c ^ ((r >> 1) & 3); }

// ---------------- weight fake-quant (6-bit, per-tensor absmax) ----------------
struct QTask { const float* src; bf16* dst; int n; int slot; int blk0; };
struct QTasks { QTask t[8]; };

__global__ __launch_bounds__(256) void absmax_all(QTasks qt, unsigned* amax) {
  int ti = 0;
  #pragma unroll
  for (int i = 1; i < 8; ++i) if ((int)blockIdx.x >= qt.t[i].blk0) ti = i;
  const QTask tk = qt.t[ti];
  const int base = (blockIdx.x - tk.blk0) * 4096;
  const float4* s4 = (const float4*)(tk.src + base);
  float m = 0.f;
  #pragma unroll
  for (int i = 0; i < 4; ++i) {
    float4 w = s4[i * 256 + threadIdx.x];
    m = fmaxf(m, fmaxf(fmaxf(fabsf(w.x), fabsf(w.y)), fmaxf(fabsf(w.z), fabsf(w.w))));
  }
  m = waveMax(m);
  __shared__ float red[4];
  if ((threadIdx.x & 63) == 0) red[threadIdx.x >> 6] = m;
  __syncthreads();
  if (threadIdx.x == 0) {
    float mm = fmaxf(fmaxf(red[0], red[1]), fmaxf(red[2], red[3]));
    atomicMax(amax + tk.slot, __float_as_uint(mm));
  }
}

__global__ __launch_bounds__(256) void quant_all(QTasks qt, const unsigned* amax) {
  int ti = 0;
  #pragma unroll
  for (int i = 1; i < 8; ++i) if ((int)blockIdx.x >= qt.t[i].blk0) ti = i;
  const QTask tk = qt.t[ti];
  const float scale = __uint_as_float(amax[tk.slot]) / 31.0f + 1e-8f;
  const int base = (blockIdx.x - tk.blk0) * 4096;
  const float4* s4 = (const float4*)(tk.src + base);
  bf16x4* d4 = (bf16x4*)(tk.dst + base);
  #pragma unroll
  for (int i = 0; i < 4; ++i) {
    float4 w = s4[i * 256 + threadIdx.x];
    bf16x4 o;
    float q;
    q = fminf(31.f, fmaxf(-31.f, rintf(w.x / scale))); o[0] = f2bf(q * scale);
    q = fminf(31.f, fmaxf(-31.f, rintf(w.y / scale))); o[1] = f2bf(q * scale);
    q = fminf(31.f, fmaxf(-31.f, rintf(w.z / scale))); o[2] = f2bf(q * scale);
    q = fminf(31.f, fmaxf(-31.f, rintf(w.w / scale))); o[3] = f2bf(q * scale);
    d4[i * 256 + threadIdx.x] = o;
  }
}

// ---------------- per-head stalk premultiply ----------------
__global__ __launch_bounds__(256) void premul_stalk(const bf16* __restrict__ Su,
                                                    const bf16* __restrict__ Sv,
                                                    const bf16* __restrict__ Wqk,
                                                    bf16* __restrict__ Wdst) {
  const int tensor = blockIdx.x >> 4;
  const int h = blockIdx.x & 15;
  const int c0 = blockIdx.y * 64;
  const bf16* S = tensor ? Sv : Su;
  const bf16* W = Wqk + (size_t)tensor * 1024 * 1024 + (size_t)h * 64 * 1024;
  bf16* D = Wdst + (size_t)tensor * 1024 * 1024 + (size_t)h * 64 * 1024;
  const int tid = threadIdx.x;
  const int i = tid >> 2;
  const int c = c0 + (tid & 3) * 16;
  bf16x8 srow[8];
  #pragma unroll
  for (int k = 0; k < 8; ++k) srow[k] = *(const bf16x8*)(S + i * 64 + k * 8);
  float acc[16] = {};
  #pragma unroll
  for (int j = 0; j < 64; ++j) {
    const float s = (float)srow[j >> 3][j & 7];
    const bf16x8 w0 = *(const bf16x8*)(W + (size_t)j * 1024 + c);
    const bf16x8 w1 = *(const bf16x8*)(W + (size_t)j * 1024 + c + 8);
    #pragma unroll
    for (int k = 0; k < 8; ++k) { acc[k] += s * (float)w0[k]; acc[8 + k] += s * (float)w1[k]; }
  }
  bf16x8 o0, o1;
  #pragma unroll
  for (int k = 0; k < 8; ++k) { o0[k] = f2bf(acc[k]); o1[k] = f2bf(acc[8 + k]); }
  *(bf16x8*)(D + (size_t)i * 1024 + c) = o0;
  *(bf16x8*)(D + (size_t)i * 1024 + c + 8) = o1;
}

// ---------------- layernorm (fp32 in, bf16 out), D = 1024 ----------------
__global__ __launch_bounds__(256) void ln_kernel(const float* __restrict__ x,
                                                 const float* __restrict__ g,
                                                 const float* __restrict__ b,
                                                 bf16* __restrict__ out) {
  const int row = blockIdx.x, tid = threadIdx.x;
  const float4 v = ((const float4*)(x + (size_t)row * 1024))[tid];
  float s = v.x + v.y + v.z + v.w;
  float ss = v.x * v.x + v.y * v.y + v.z * v.z + v.w * v.w;
  s = waveSum(s); ss = waveSum(ss);
  __shared__ float rs[4], rq[4];
  if ((tid & 63) == 0) { rs[tid >> 6] = s; rq[tid >> 6] = ss; }
  __syncthreads();
  s = rs[0] + rs[1] + rs[2] + rs[3];
  ss = rq[0] + rq[1] + rq[2] + rq[3];
  const float mu = s * (1.f / 1024.f);
  const float var = ss * (1.f / 1024.f) - mu * mu;
  const float rstd = rsqrtf(var + 1e-5f);
  const float4 gv = ((const float4*)g)[tid];
  const float4 bv = ((const float4*)b)[tid];
  bf16x4 o;
  o[0] = f2bf((v.x - mu) * rstd * gv.x + bv.x);
  o[1] = f2bf((v.y - mu) * rstd * gv.y + bv.y);
  o[2] = f2bf((v.z - mu) * rstd * gv.z + bv.z);
  o[3] = f2bf((v.w - mu) * rstd * gv.w + bv.w);
  ((bf16x4*)(out + (size_t)row * 1024))[tid] = o;
}

// ---------------- GEMM: C[M,N] = A[M,K] * B[N,K]^T, BK=32, swizzled LDS ----------------
template <int EPI>
__global__ __launch_bounds__(256) void gemm_bt(const bf16* __restrict__ A,
                                               const bf16* __restrict__ B,
                                               bf16* __restrict__ C,
                                               bf16* __restrict__ Qsb,
                                               bf16* __restrict__ Ksb,
                                               bf16* __restrict__ Vtg,
                                               int M, int N, int K) {
  constexpr int BM = 128, BN = 128, BK = 32;
  __shared__ bf16 As[BM * BK];
  __shared__ bf16 Bs[BN * BK];
  const int tid = threadIdx.x;
  const int wave = tid >> 6, lane = tid & 63, quad = lane >> 4, l16 = lane & 15;
  const int bm0 = blockIdx.y * BM, bn0 = blockIdx.x * BN;
  const int wr = (wave >> 1) * 64, wc = (wave & 1) * 64;
  f32x4 acc[4][4] = {};

  for (int k0 = 0; k0 < K; k0 += BK) {
    __syncthreads();
    #pragma unroll
    for (int i = 0; i < 2; ++i) {
      const int id = tid + i * 256;
      const int r = id >> 2, c = swz(r, id & 3) * 8;
      __builtin_amdgcn_global_load_lds(
          (GLOBAL_AS void*)(A + (size_t)(bm0 + r) * K + k0 + c),
          (LDS_AS void*)(As + (size_t)(i * 256 + wave * 64) * 8), 16, 0, 0);
      __builtin_amdgcn_global_load_lds(
          (GLOBAL_AS void*)(B + (size_t)(bn0 + r) * K + k0 + c),
          (LDS_AS void*)(Bs + (size_t)(i * 256 + wave * 64) * 8), 16, 0, 0);
    }
    __syncthreads();
    bf16x8 af[4], bfr[4];
    #pragma unroll
    for (int mi = 0; mi < 4; ++mi) {
      const int r = wr + mi * 16 + l16;
      af[mi] = *(const bf16x8*)(As + (r * 4 + swz(r, quad)) * 8);
    }
    #pragma unroll
    for (int ni = 0; ni < 4; ++ni) {
      const int r = wc + ni * 16 + l16;
      bfr[ni] = *(const bf16x8*)(Bs + (r * 4 + swz(r, quad)) * 8);
    }
    #pragma unroll
    for (int mi = 0; mi < 4; ++mi)
      #pragma unroll
      for (int ni = 0; ni < 4; ++ni)
        acc[mi][ni] = __builtin_amdgcn_mfma_f32_16x16x32_bf16(af[mi], bfr[ni], acc[mi][ni], 0, 0, 0);
  }

  #pragma unroll
  for (int ni = 0; ni < 4; ++ni) {
    const int col = bn0 + wc + ni * 16 + l16;
    if constexpr (EPI == 0) {
      #pragma unroll
      for (int mi = 0; mi < 4; ++mi)
        #pragma unroll
        for (int reg = 0; reg < 4; ++reg) {
          const int row = bm0 + wr + mi * 16 + quad * 4 + reg;
          C[(size_t)row * N + col] = f2bf(acc[mi][ni][reg]);
        }
    } else {
      if (col < 2048) {
        const int h = (col >> 6) & 15, s = col & 63;
        bf16* dst = (col < 1024 ? Qsb : Ksb) + (size_t)h * 1024 * 64 + s;
        #pragma unroll
        for (int mi = 0; mi < 4; ++mi)
          #pragma unroll
          for (int reg = 0; reg < 4; ++reg) {
            const int row = bm0 + wr + mi * 16 + quad * 4 + reg;
            const int b = row >> 10, t = row & 1023;
            dst[((size_t)b * 16 * 1024 + t) * 64] = f2bf(acc[mi][ni][reg]);
          }
      } else {
        const int h = (col >> 6) & 15, s = col & 63;
        const int bq = bm0 >> 10;
        bf16* vdst = Vtg + (((size_t)(bq * 16 + h) * 64 + s) * 1024) + (bm0 & 1023) + wr + quad * 4;
        #pragma unroll
        for (int mi = 0; mi < 4; ++mi) {
          bf16x4 vv;
          #pragma unroll
          for (int reg = 0; reg < 4; ++reg) vv[reg] = f2bf(acc[mi][ni][reg]);
          *(bf16x4*)(vdst + mi * 16) = vv;
        }
      }
    }
  }
}

// ---------------- split-K GEMM, BK=32, bf16 partials, XCD row-band swizzle ----------------
__global__ __launch_bounds__(256) void gemm_bt_split(const bf16* __restrict__ A,
                                                     const bf16* __restrict__ B,
                                                     bf16* __restrict__ P,
                                                     int M, int N, int Kfull, int Kper) {
  constexpr int BM = 128, BN = 128, BK = 32;
  __shared__ bf16 As[BM * BK];
  __shared__ bf16 Bs[BN * BK];
  const int tid = threadIdx.x;
  const int wave = tid >> 6, lane = tid & 63, quad = lane >> 4, l16 = lane & 15;
  const int lin = blockIdx.x + 8 * blockIdx.y;
  const int xcd = lin & 7, idx = lin >> 3;
  const int bm0 = (xcd * 4 + (idx & 3)) * BM;
  const int bn0 = (idx >> 2) * BN;
  const int wr = (wave >> 1) * 64, wc = (wave & 1) * 64;
  const int kbeg = blockIdx.z * Kper;
  const int kend = min(kbeg + Kper, Kfull);
  bf16* Pz = P + (size_t)blockIdx.z * M * N;
  f32x4 acc[4][4] = {};

  for (int k0 = kbeg; k0 < kend; k0 += BK) {
    __syncthreads();
    #pragma unroll
    for (int i = 0; i < 2; ++i) {
      const int id = tid + i * 256;
      const int r = id >> 2, c = swz(r, id & 3) * 8;
      __builtin_amdgcn_global_load_lds(
          (GLOBAL_AS void*)(A + (size_t)(bm0 + r) * Kfull + k0 + c),
          (LDS_AS void*)(As + (size_t)(i * 256 + wave * 64) * 8), 16, 0, 0);
      __builtin_amdgcn_global_load_lds(
          (GLOBAL_AS void*)(B + (size_t)(bn0 + r) * Kfull + k0 + c),
          (LDS_AS void*)(Bs + (size_t)(i * 256 + wave * 64) * 8), 16, 0, 0);
    }
    __syncthreads();
    bf16x8 af[4], bfr[4];
    #pragma unroll
    for (int mi = 0; mi < 4; ++mi) {
      const int r = wr + mi * 16 + l16;
      af[mi] = *(const bf16x8*)(As + (r * 4 + swz(r, quad)) * 8);
    }
    #pragma unroll
    for (int ni = 0; ni < 4; ++ni) {
      const int r = wc + ni * 16 + l16;
      bfr[ni] = *(const bf16x8*)(Bs + (r * 4 + swz(r, quad)) * 8);
    }
    #pragma unroll
    for (int mi = 0; mi < 4; ++mi)
      #pragma unroll
      for (int ni = 0; ni < 4; ++ni)
        acc[mi][ni] = __builtin_amdgcn_mfma_f32_16x16x32_bf16(af[mi], bfr[ni], acc[mi][ni], 0, 0, 0);
  }

  #pragma unroll
  for (int mi = 0; mi < 4; ++mi)
    #pragma unroll
    for (int ni = 0; ni < 4; ++ni)
      #pragma unroll
      for (int reg = 0; reg < 4; ++reg) {
        const int row = bm0 + wr + mi * 16 + quad * 4 + reg;
        const int col = bn0 + wc + ni * 16 + l16;
        Pz[(size_t)row * N + col] = f2bf(acc[mi][ni][reg]);
      }
}

// ---------------- reduce wo-splits(3, bf16) + residual + LN2 fused ----------------
__global__ __launch_bounds__(256) void reduce_wo_ln(const float* __restrict__ x,
                                                    const bf16* __restrict__ P,
                                                    const float* __restrict__ g,
                                                    const float* __restrict__ b,
                                                    float* __restrict__ y,
                                                    bf16* __restrict__ lnout) {
  constexpr size_t MN = (size_t)4096 * 1024;
  const int row = blockIdx.x, tid = threadIdx.x;
  const size_t base = (size_t)row * 1024;
  const float4 vx = ((const float4*)(x + base))[tid];
  const bf16x4 p0 = ((const bf16x4*)(P + base))[tid];
  const bf16x4 p1 = ((const bf16x4*)(P + base + MN))[tid];
  const bf16x4 p2 = ((const bf16x4*)(P + base + 2 * MN))[tid];
  float4 v;
  v.x = vx.x + (float)p0[0] + (float)p1[0] + (float)p2[0];
  v.y = vx.y + (float)p0[1] + (float)p1[1] + (float)p2[1];
  v.z = vx.z + (float)p0[2] + (float)p1[2] + (float)p2[2];
  v.w = vx.w + (float)p0[3] + (float)p1[3] + (float)p2[3];
  ((float4*)(y + base))[tid] = v;
  float s = v.x + v.y + v.z + v.w;
  float ss = v.x * v.x + v.y * v.y + v.z * v.z + v.w * v.w;
  s = waveSum(s); ss = waveSum(ss);
  __shared__ float rs[4], rq[4];
  if ((tid & 63) == 0) { rs[tid >> 6] = s; rq[tid >> 6] = ss; }
  __syncthreads();
  s = rs[0] + rs[1] + rs[2] + rs[3];
  ss = rq[0] + rq[1] + rq[2] + rq[3];
  const float mu = s * (1.f / 1024.f);
  const float var = ss * (1.f / 1024.f) - mu * mu;
  const float rstd = rsqrtf(var + 1e-5f);
  const float4 gv = ((const float4*)g)[tid];
  const float4 bv = ((const float4*)b)[tid];
  bf16x4 o;
  o[0] = f2bf((v.x - mu) * rstd * gv.x + bv.x);
  o[1] = f2bf((v.y - mu) * rstd * gv.y + bv.y);
  o[2] = f2bf((v.z - mu) * rstd * gv.z + bv.z);
  o[3] = f2bf((v.w - mu) * rstd * gv.w + bv.w);
  ((bf16x4*)(lnout + base))[tid] = o;
}

// ---------------- reduce down-splits(3, bf16) + residual (in-place on y) ----------------
__global__ __launch_bounds__(256) void reduce_down(float* __restrict__ y,
                                                   const bf16* __restrict__ P) {
  constexpr size_t MN = (size_t)4096 * 1024;
  const size_t i = (size_t)blockIdx.x * 256 + threadIdx.x;
  const float4 vy = ((const float4*)y)[i];
  const bf16x4 p0 = ((const bf16x4*)P)[i];
  const bf16x4 p1 = ((const bf16x4*)(P + MN))[i];
  const bf16x4 p2 = ((const bf16x4*)(P + 2 * MN))[i];
  float4 v;
  v.x = vy.x + (float)p0[0] + (float)p1[0] + (float)p2[0];
  v.y = vy.y + (float)p0[1] + (float)p1[1] + (float)p2[1];
  v.z = vy.z + (float)p0[2] + (float)p1[2] + (float)p2[2];
  v.w = vy.w + (float)p0[3] + (float)p1[3] + (float)p2[3];
  ((float4*)y)[i] = v;
}

// ---------------- flash attention: 128-row Q-tile, fixed-shift softmax ----------------
// Each block owns 2 Q-subtiles (t0, t0+64) sharing every staged K/V tile:
// staging loads, barriers, and P-LDS round-trips per MFMA all halve vs 64-row blocks.
__global__ __launch_bounds__(256) void attn_flash(const bf16* __restrict__ Qs,
                                                  const bf16* __restrict__ Ks,
                                                  const bf16* __restrict__ Vtg,
                                                  const float* __restrict__ p_scale_ptr,
                                                  bf16* __restrict__ out) {
  constexpr int LDP = 72;
  const int bh = blockIdx.x;
  const int b = bh >> 4, h = bh & 15;
  const int qt = 7 - (int)blockIdx.y;       // heavy blocks first
  const int t0 = qt * 128;
  const int tid = threadIdx.x, wave = tid >> 6, lane = tid & 63, quad = lane >> 4, l16 = lane & 15;

  __shared__ bf16 Kst[64 * LDP];
  __shared__ bf16 Vt[64 * LDP];
  __shared__ bf16 Plds[4][16 * LDP];

  const float pscale2 = p_scale_ptr[0] * 1.44269504f;
  const float sc2 = 0.125f * 1.44269504f;

  const bf16* Qb = Qs + ((size_t)bh * 1024 + t0) * 64;
  const bf16* Kb = Ks + ((size_t)bh * 1024) * 64;
  const bf16* Vb = Vtg + ((size_t)bh * 64) * 1024;

  const int trow = wave * 16 + l16;
  const bf16x8 qA0 = *(const bf16x8*)(Qb + trow * 64 + quad * 8);
  const bf16x8 qA1 = *(const bf16x8*)(Qb + trow * 64 + 32 + quad * 8);
  const bf16x8 qB0 = *(const bf16x8*)(Qb + (64 + trow) * 64 + quad * 8);
  const bf16x8 qB1 = *(const bf16x8*)(Qb + (64 + trow) * 64 + 32 + quad * 8);

  float lsumA[4] = {0.f, 0.f, 0.f, 0.f}, lsumB[4] = {0.f, 0.f, 0.f, 0.f};
  f32x4 OA[4] = {}, OB[4] = {};

  bf16x8 st[4];
  auto loadTile = [&](int u0) {
    #pragma unroll
    for (int i = 0; i < 2; ++i) {
      const int cid = tid + i * 256;
      st[i] = *(const bf16x8*)(Kb + (size_t)u0 * 64 + cid * 8);
      st[2 + i] = *(const bf16x8*)(Vb + (size_t)(cid >> 3) * 1024 + u0 + (cid & 7) * 8);
    }
  };
  loadTile(0);

  const int utmax = 2 * qt + 1;
  for (int ut = 0; ut <= utmax; ++ut) {
    const int u0 = ut * 64;
    #pragma unroll
    for (int i = 0; i < 2; ++i) {
      const int cid = tid + i * 256;
      const int r = cid >> 3, c8 = (cid & 7) * 8;
      *(bf16x8*)(Kst + r * LDP + c8) = st[i];
      *(bf16x8*)(Vt + r * LDP + c8) = st[2 + i];
    }
    __syncthreads();
    if (ut < utmax) loadTile(u0 + 64);

    // K fragments shared by both Q-subtiles
    bf16x8 k0[4], k1[4], v0[4], v1[4];
    #pragma unroll
    for (int ni = 0; ni < 4; ++ni) {
      k0[ni] = *(const bf16x8*)(Kst + (ni * 16 + l16) * LDP + quad * 8);
      k1[ni] = *(const bf16x8*)(Kst + (ni * 16 + l16) * LDP + 32 + quad * 8);
      v0[ni] = *(const bf16x8*)(Vt + (ni * 16 + l16) * LDP + quad * 8);
      v1[ni] = *(const bf16x8*)(Vt + (ni * 16 + l16) * LDP + 32 + quad * 8);
    }

    #pragma unroll
    for (int half = 0; half < 2; ++half) {
      const int tbase = t0 + half * 64;
      // tile's last contributing u-tile: u0 <= tbase+63
      if (u0 > tbase + 63) continue;          // wave-uniform (only trims half=0 at ut=utmax)
      const bf16x8 q0 = half ? qB0 : qA0;
      const bf16x8 q1 = half ? qB1 : qA1;
      float* lsum = half ? lsumB : lsumA;
      f32x4* Oacc = half ? OB : OA;
      const bool diag = (u0 + 63 >= tbase);    // masking needed only near diagonal

      f32x4 sc[4];
      #pragma unroll
      for (int ni = 0; ni < 4; ++ni) {
        f32x4 z = {};
        z = __builtin_amdgcn_mfma_f32_16x16x32_bf16(q0, k0[ni], z, 0, 0, 0);
        z = __builtin_amdgcn_mfma_f32_16x16x32_bf16(q1, k1[ni], z, 0, 0, 0);
        sc[ni] = z;
      }
      #pragma unroll
      for (int reg = 0; reg < 4; ++reg) {
        const int t = tbase + wave * 16 + quad * 4 + reg;
        #pragma unroll
        for (int ni = 0; ni < 4; ++ni) {
          const int u = u0 + ni * 16 + l16;
          const int d = t - u;
          float v = sc[ni][reg] * sc2;
          if (diag && d < 0) {
            v = -1e30f;
          } else {
            const float bias = (d == 0) ? 1.0f : (float)__builtin_ctz(d) * 0.0625f;
            v += pscale2 * bias;
          }
          const float p = exp2f(fminf(v, 80.f) - 8.f);
          lsum[reg] += p;
          Plds[wave][(quad * 4 + reg) * LDP + ni * 16 + l16] = f2bf(p);
        }
      }
      const bf16x8 pf0 = *(const bf16x8*)(&Plds[wave][l16 * LDP + quad * 8]);
      const bf16x8 pf1 = *(const bf16x8*)(&Plds[wave][l16 * LDP + 32 + quad * 8]);
      #pragma unroll
      for (int ni = 0; ni < 4; ++ni) {
        Oacc[ni] = __builtin_amdgcn_mfma_f32_16x16x32_bf16(pf0, v0[ni], Oacc[ni], 0, 0, 0);
        Oacc[ni] = __builtin_amdgcn_mfma_f32_16x16x32_bf16(pf1, v1[ni], Oacc[ni], 0, 0, 0);
      }
    }
    __syncthreads();
  }

  #pragma unroll
  for (int reg = 0; reg < 4; ++reg) {
    float ra = lsumA[reg], rb = lsumB[reg];
    #pragma unroll
    for (int o = 1; o < 16; o <<= 1) { ra += __shfl_xor(ra, o); rb += __shfl_xor(rb, o); }
    lsumA[reg] = 1.0f / ra;
    lsumB[reg] = 1.0f / rb;
  }

  #pragma unroll
  for (int ni = 0; ni < 4; ++ni)
    #pragma unroll
    for (int reg = 0; reg < 4; ++reg) {
      const int tA = t0 + wave * 16 + quad * 4 + reg;
      out[((size_t)(b * 1024 + tA)) * 1024 + h * 64 + ni * 16 + l16] = f2bf(OA[ni][reg] * lsumA[reg]);
      out[((size_t)(b * 1024 + tA + 64)) * 1024 + h * 64 + ni * 16 + l16] = f2bf(OB[ni][reg] * lsumB[reg]);
    }
}

// ---------------- SO(2) rotation + LN(3072) + SiLU, bf16 in/out ----------------
__global__ __launch_bounds__(256) void rot_ln_silu(const bf16* __restrict__ hb,
                                                   const float* __restrict__ theta,
                                                   const float* __restrict__ g,
                                                   const float* __restrict__ bb,
                                                   bf16* __restrict__ out) {
  const int row = blockIdx.x, tid = threadIdx.x;
  const bf16* hr = hb + (size_t)row * 3072;
  float r[12];
  float s = 0.f, ss = 0.f;
  #pragma unroll
  for (int i = 0; i < 6; ++i) {
    const int p = tid + i * 256;
    const bf16x2 ab = *(const bf16x2*)(hr + 2 * p);
    const float a = (float)ab[0], b_ = (float)ab[1];
    const float th = theta[p];
    const float c = cosf(th), sn = sinf(th);
    const float r0 = c * a - sn * b_;
    const float r1 = sn * a + c * b_;
    r[2 * i] = r0; r[2 * i + 1] = r1;
    s += r0 + r1;
    ss += r0 * r0 + r1 * r1;
  }
  s = waveSum(s); ss = waveSum(ss);
  __shared__ float rs_[4], rq_[4];
  if ((tid & 63) == 0) { rs_[tid >> 6] = s; rq_[tid >> 6] = ss; }
  __syncthreads();
  s = rs_[0] + rs_[1] + rs_[2] + rs_[3];
  ss = rq_[0] + rq_[1] + rq_[2] + rq_[3];
  const float mu = s * (1.f / 3072.f);
  const float var = ss * (1.f / 3072.f) - mu * mu;
  const float rstd = rsqrtf(var + 1e-5f);
  bf16* orow = out + (size_t)row * 3072;
  #pragma unroll
  for (int i = 0; i < 6; ++i) {
    const int p = tid + i * 256;
    const float2 gv = *(const float2*)(g + 2 * p);
    const float2 bv = *(const float2*)(bb + 2 * p);
    const float y0 = (r[2 * i] - mu) * rstd * gv.x + bv.x;
    const float y1 = (r[2 * i + 1] - mu) * rstd * gv.y + bv.y;
    const float o0 = y0 / (1.f + expf(-y0));
    const float o1 = y1 / (1.f + expf(-y1));
    bf16x2 o; o[0] = f2bf(o0); o[1] = f2bf(o1);
    *(bf16x2*)(orow + 2 * p) = o;
  }
}

// ---------------- host launch ----------------
extern "C" void kernel_launch(void* const* d_in, const int* in_sizes, int n_in,
                              void* d_out, int out_size, void* d_ws, size_t ws_size,
                              hipStream_t stream) {
  const float* x    = (const float*)d_in[0];
  const float* wq   = (const float*)d_in[1];
  const float* wk   = (const float*)d_in[2];
  const float* wv   = (const float*)d_in[3];
  const float* wo   = (const float*)d_in[4];
  const float* su   = (const float*)d_in[5];
  const float* sv   = (const float*)d_in[6];
  const float* psc  = (const float*)d_in[7];
  const float* n1g  = (const float*)d_in[8];
  const float* n1b  = (const float*)d_in[9];
  const float* n2g  = (const float*)d_in[10];
  const float* n2b  = (const float*)d_in[11];
  const float* wup  = (const float*)d_in[12];
  const float* wdn  = (const float*)d_in[13];
  const float* th   = (const float*)d_in[14];
  const float* mg   = (const float*)d_in[15];
  const float* mb   = (const float*)d_in[16];
  float* outp = (float*)d_out;

  char* ws = (char*)d_ws;
  size_t off = 0;
  auto alloc = [&](size_t bytes) { size_t o = off; off += (bytes + 255) & ~(size_t)255; return o; };
  constexpr size_t MB84 = (size_t)4096 * 1024 * 2;
  unsigned* amax = (unsigned*)(ws + alloc(32));
  bf16* Su    = (bf16*)(ws + alloc(4096 * 2));
  bf16* Sv    = (bf16*)(ws + alloc(4096 * 2));
  bf16* Wo    = (bf16*)(ws + alloc((size_t)1024 * 1024 * 2));
  bf16* Wup   = (bf16*)(ws + alloc((size_t)3072 * 1024 * 2));
  bf16* Wdn   = (bf16*)(ws + alloc((size_t)1024 * 3072 * 2));
  bf16* Wqkv2 = (bf16*)(ws + alloc((size_t)3072 * 1024 * 2));
  bf16* Wqk   = (bf16*)(ws + alloc((size_t)2048 * 1024 * 2));
  bf16* lnbuf = (bf16*)(ws + alloc(MB84));
  char* arena = ws + alloc(6 * MB84);
  bf16* Qsb   = (bf16*)(arena);
  bf16* Ksb   = (bf16*)(arena + MB84);
  bf16* Vtg   = (bf16*)(arena + 2 * MB84);
  bf16* attno = (bf16*)(arena + 3 * MB84);
  bf16* hbuf  = (bf16*)(arena);
  bf16* gbuf  = (bf16*)(arena + 3 * MB84);
  bf16* Pbuf  = (bf16*)(ws + alloc((size_t)3 * 4096 * 1024 * 2));

  hipMemsetAsync(amax, 0, 32, stream);

  QTasks qt;
  int blk = 0;
  auto add = [&](int i, const float* s, bf16* d, int n) {
    qt.t[i].src = s; qt.t[i].dst = d; qt.t[i].n = n; qt.t[i].slot = i; qt.t[i].blk0 = blk;
    blk += n / 4096;
  };
  add(0, wq, Wqk, 1024 * 1024);
  add(1, wk, Wqk + (size_t)1024 * 1024, 1024 * 1024);
  add(2, wv, Wqkv2 + (size_t)2048 * 1024, 1024 * 1024);
  add(3, wo, Wo, 1024 * 1024);
  add(4, su, Su, 4096);
  add(5, sv, Sv, 4096);
  add(6, wup, Wup, 3072 * 1024);
  add(7, wdn, Wdn, 3072 * 1024);

  absmax_all<<<blk, 256, 0, stream>>>(qt, amax);
  quant_all<<<blk, 256, 0, stream>>>(qt, amax);
  premul_stalk<<<dim3(32, 16), 256, 0, stream>>>(Su, Sv, Wqk, Wqkv2);

  ln_kernel<<<4096, 256, 0, stream>>>(x, n1g, n1b, lnbuf);
  gemm_bt<1><<<dim3(24, 32), 256, 0, stream>>>(lnbuf, Wqkv2, nullptr, Qsb, Ksb, Vtg, 4096, 3072, 1024);
  attn_flash<<<dim3(64, 8), 256, 0, stream>>>(Qsb, Ksb, Vtg, psc, attno);
  gemm_bt_split<<<dim3(8, 32, 3), 256, 0, stream>>>(attno, Wo, Pbuf, 4096, 1024, 1024, 352);
  reduce_wo_ln<<<4096, 256, 0, stream>>>(x, Pbuf, n2g, n2b, outp, lnbuf);
  gemm_bt<0><<<dim3(24, 32), 256, 0, stream>>>(lnbuf, Wup, hbuf, nullptr, nullptr, nullptr, 4096, 3072, 1024);
  rot_ln_silu<<<4096, 256, 0, stream>>>(hbuf, th, mg, mb, gbuf);
  gemm_bt_split<<<dim3(8, 32, 3), 256, 0, stream>>>(gbuf, Wdn, Pbuf, 4096, 1024, 3072, 1024);
  reduce_down<<<4096, 256, 0, stream>>>(outp, Pbuf);
}

// Round 11
// 367.052 us; speedup vs baseline: 1.0724x; 1.0724x over previous
//
#include <hip/hip_runtime.h>
#include <stdint.h>

typedef __bf16 bf16;
typedef __attribute__((ext_vector_type(8))) __bf16 bf16x8;
typedef __attribute__((ext_vector_type(4))) __bf16 bf16x4;
typedef __attribute__((ext_vector_type(2))) __bf16 bf16x2;
typedef __attribute__((ext_vector_type(4))) float f32x4;
typedef __attribute__((ext_vector_type(16))) float f32x16;

#define GLOBAL_AS __attribute__((address_space(1)))
#define LDS_AS __attribute__((address_space(3)))

static __device__ __forceinline__ bf16 f2bf(float f) {
  unsigned u = __builtin_bit_cast(unsigned, f);
  u += 0x7fffu + ((u >> 16) & 1u);
  unsigned short h = (unsigned short)(u >> 16);
  return __builtin_bit_cast(bf16, h);
}

static __device__ __forceinline__ float waveSum(float v) {
  #pragma unroll
  for (int o = 32; o > 0; o >>= 1) v += __shfl_xor(v, o);
  return v;
}
static __device__ __forceinline__ float waveMax(float v) {
  #pragma unroll
  for (int o = 32; o > 0; o >>= 1) v = fmaxf(v, __shfl_xor(v, o));
  return v;
}

// BK=32 LDS swizzle (R6-proven: 0 bank conflicts): LDS slot q of row r holds
// global chunk q^((r>>1)&3); reader wanting global chunk c reads slot swz(r,c).
static __device__ __forceinline__ int swz(int r, int c) { return c ^ ((r >> 1) & 3); }

// ---------------- weight fake-quant (6-bit, per-tensor absmax) ----------------
struct QTask { const float* src; bf16* dst; int n; int slot; int blk0; };
struct QTasks { QTask t[8]; };

__global__ __launch_bounds__(256) void absmax_all(QTasks qt, unsigned* amax) {
  int ti = 0;
  #pragma unroll
  for (int i = 1; i < 8; ++i) if ((int)blockIdx.x >= qt.t[i].blk0) ti = i;
  const QTask tk = qt.t[ti];
  const int base = (blockIdx.x - tk.blk0) * 4096;
  const float4* s4 = (const float4*)(tk.src + base);
  float m = 0.f;
  #pragma unroll
  for (int i = 0; i < 4; ++i) {
    float4 w = s4[i * 256 + threadIdx.x];
    m = fmaxf(m, fmaxf(fmaxf(fabsf(w.x), fabsf(w.y)), fmaxf(fabsf(w.z), fabsf(w.w))));
  }
  m = waveMax(m);
  __shared__ float red[4];
  if ((threadIdx.x & 63) == 0) red[threadIdx.x >> 6] = m;
  __syncthreads();
  if (threadIdx.x == 0) {
    float mm = fmaxf(fmaxf(red[0], red[1]), fmaxf(red[2], red[3]));
    atomicMax(amax + tk.slot, __float_as_uint(mm));
  }
}

__global__ __launch_bounds__(256) void quant_all(QTasks qt, const unsigned* amax) {
  int ti = 0;
  #pragma unroll
  for (int i = 1; i < 8; ++i) if ((int)blockIdx.x >= qt.t[i].blk0) ti = i;
  const QTask tk = qt.t[ti];
  const float scale = __uint_as_float(amax[tk.slot]) / 31.0f + 1e-8f;
  const int base = (blockIdx.x - tk.blk0) * 4096;
  const float4* s4 = (const float4*)(tk.src + base);
  bf16x4* d4 = (bf16x4*)(tk.dst + base);
  #pragma unroll
  for (int i = 0; i < 4; ++i) {
    float4 w = s4[i * 256 + threadIdx.x];
    bf16x4 o;
    float q;
    q = fminf(31.f, fmaxf(-31.f, rintf(w.x / scale))); o[0] = f2bf(q * scale);
    q = fminf(31.f, fmaxf(-31.f, rintf(w.y / scale))); o[1] = f2bf(q * scale);
    q = fminf(31.f, fmaxf(-31.f, rintf(w.z / scale))); o[2] = f2bf(q * scale);
    q = fminf(31.f, fmaxf(-31.f, rintf(w.w / scale))); o[3] = f2bf(q * scale);
    d4[i * 256 + threadIdx.x] = o;
  }
}

// ---------------- per-head stalk premultiply ----------------
__global__ __launch_bounds__(256) void premul_stalk(const bf16* __restrict__ Su,
                                                    const bf16* __restrict__ Sv,
                                                    const bf16* __restrict__ Wqk,
                                                    bf16* __restrict__ Wdst) {
  const int tensor = blockIdx.x >> 4;
  const int h = blockIdx.x & 15;
  const int c0 = blockIdx.y * 64;
  const bf16* S = tensor ? Sv : Su;
  const bf16* W = Wqk + (size_t)tensor * 1024 * 1024 + (size_t)h * 64 * 1024;
  bf16* D = Wdst + (size_t)tensor * 1024 * 1024 + (size_t)h * 64 * 1024;
  const int tid = threadIdx.x;
  const int i = tid >> 2;
  const int c = c0 + (tid & 3) * 16;
  bf16x8 srow[8];
  #pragma unroll
  for (int k = 0; k < 8; ++k) srow[k] = *(const bf16x8*)(S + i * 64 + k * 8);
  float acc[16] = {};
  #pragma unroll
  for (int j = 0; j < 64; ++j) {
    const float s = (float)srow[j >> 3][j & 7];
    const bf16x8 w0 = *(const bf16x8*)(W + (size_t)j * 1024 + c);
    const bf16x8 w1 = *(const bf16x8*)(W + (size_t)j * 1024 + c + 8);
    #pragma unroll
    for (int k = 0; k < 8; ++k) { acc[k] += s * (float)w0[k]; acc[8 + k] += s * (float)w1[k]; }
  }
  bf16x8 o0, o1;
  #pragma unroll
  for (int k = 0; k < 8; ++k) { o0[k] = f2bf(acc[k]); o1[k] = f2bf(acc[8 + k]); }
  *(bf16x8*)(D + (size_t)i * 1024 + c) = o0;
  *(bf16x8*)(D + (size_t)i * 1024 + c + 8) = o1;
}

// ---------------- layernorm (fp32 in, bf16 out), D = 1024 ----------------
__global__ __launch_bounds__(256) void ln_kernel(const float* __restrict__ x,
                                                 const float* __restrict__ g,
                                                 const float* __restrict__ b,
                                                 bf16* __restrict__ out) {
  const int row = blockIdx.x, tid = threadIdx.x;
  const float4 v = ((const float4*)(x + (size_t)row * 1024))[tid];
  float s = v.x + v.y + v.z + v.w;
  float ss = v.x * v.x + v.y * v.y + v.z * v.z + v.w * v.w;
  s = waveSum(s); ss = waveSum(ss);
  __shared__ float rs[4], rq[4];
  if ((tid & 63) == 0) { rs[tid >> 6] = s; rq[tid >> 6] = ss; }
  __syncthreads();
  s = rs[0] + rs[1] + rs[2] + rs[3];
  ss = rq[0] + rq[1] + rq[2] + rq[3];
  const float mu = s * (1.f / 1024.f);
  const float var = ss * (1.f / 1024.f) - mu * mu;
  const float rstd = rsqrtf(var + 1e-5f);
  const float4 gv = ((const float4*)g)[tid];
  const float4 bv = ((const float4*)b)[tid];
  bf16x4 o;
  o[0] = f2bf((v.x - mu) * rstd * gv.x + bv.x);
  o[1] = f2bf((v.y - mu) * rstd * gv.y + bv.y);
  o[2] = f2bf((v.z - mu) * rstd * gv.z + bv.z);
  o[3] = f2bf((v.w - mu) * rstd * gv.w + bv.w);
  ((bf16x4*)(out + (size_t)row * 1024))[tid] = o;
}

// ---------------- GEMM: C[M,N] = A[M,K] * B[N,K]^T, BK=32, 32x32x16 MFMA ----------------
// Wave computes 64x64 as 2x2 tiles of 32x32. A/B frag: m=lane&31, k=(lane>>5)*8+j.
// C/D: col=lane&31, row=(reg&3)+8*(reg>>2)+4*(lane>>5), reg in [0,16).
template <int EPI>
__global__ __launch_bounds__(256) void gemm_bt(const bf16* __restrict__ A,
                                               const bf16* __restrict__ B,
                                               bf16* __restrict__ C,
                                               bf16* __restrict__ Qsb,
                                               bf16* __restrict__ Ksb,
                                               bf16* __restrict__ Vtg,
                                               int M, int N, int K) {
  constexpr int BM = 128, BN = 128, BK = 32;
  __shared__ bf16 As[BM * BK];
  __shared__ bf16 Bs[BN * BK];
  const int tid = threadIdx.x;
  const int wave = tid >> 6, lane = tid & 63;
  const int l31 = lane & 31, khalf = lane >> 5;
  const int bm0 = blockIdx.y * BM, bn0 = blockIdx.x * BN;
  const int wr = (wave >> 1) * 64, wc = (wave & 1) * 64;
  f32x16 acc[2][2] = {};

  for (int k0 = 0; k0 < K; k0 += BK) {
    __syncthreads();
    #pragma unroll
    for (int i = 0; i < 2; ++i) {
      const int id = tid + i * 256;
      const int r = id >> 2, c = swz(r, id & 3) * 8;
      __builtin_amdgcn_global_load_lds(
          (GLOBAL_AS void*)(A + (size_t)(bm0 + r) * K + k0 + c),
          (LDS_AS void*)(As + (size_t)(i * 256 + wave * 64) * 8), 16, 0, 0);
      __builtin_amdgcn_global_load_lds(
          (GLOBAL_AS void*)(B + (size_t)(bn0 + r) * K + k0 + c),
          (LDS_AS void*)(Bs + (size_t)(i * 256 + wave * 64) * 8), 16, 0, 0);
    }
    __syncthreads();
    #pragma unroll
    for (int h = 0; h < 2; ++h) {
      const int c0 = h * 2 + khalf;
      bf16x8 af[2], bfr[2];
      #pragma unroll
      for (int mi = 0; mi < 2; ++mi) {
        const int r = wr + mi * 32 + l31;
        af[mi] = *(const bf16x8*)(As + (r * 4 + swz(r, c0)) * 8);
      }
      #pragma unroll
      for (int ni = 0; ni < 2; ++ni) {
        const int r = wc + ni * 32 + l31;
        bfr[ni] = *(const bf16x8*)(Bs + (r * 4 + swz(r, c0)) * 8);
      }
      #pragma unroll
      for (int mi = 0; mi < 2; ++mi)
        #pragma unroll
        for (int ni = 0; ni < 2; ++ni)
          acc[mi][ni] = __builtin_amdgcn_mfma_f32_32x32x16_bf16(af[mi], bfr[ni], acc[mi][ni], 0, 0, 0);
    }
  }

  #pragma unroll
  for (int ni = 0; ni < 2; ++ni) {
    const int col = bn0 + wc + ni * 32 + l31;
    if constexpr (EPI == 0) {
      #pragma unroll
      for (int mi = 0; mi < 2; ++mi) {
        const int rbase = bm0 + wr + mi * 32 + 4 * khalf;
        #pragma unroll
        for (int reg = 0; reg < 16; ++reg) {
          const int row = rbase + (reg & 3) + 8 * (reg >> 2);
          C[(size_t)row * N + col] = f2bf(acc[mi][ni][reg]);
        }
      }
    } else {
      if (col < 2048) {
        const int hh = (col >> 6) & 15, s = col & 63;
        bf16* dst = (col < 1024 ? Qsb : Ksb) + (size_t)hh * 1024 * 64 + s;
        #pragma unroll
        for (int mi = 0; mi < 2; ++mi) {
          const int rbase = bm0 + wr + mi * 32 + 4 * khalf;
          #pragma unroll
          for (int reg = 0; reg < 16; ++reg) {
            const int row = rbase + (reg & 3) + 8 * (reg >> 2);
            const int b = row >> 10, t = row & 1023;
            dst[((size_t)b * 16 * 1024 + t) * 64] = f2bf(acc[mi][ni][reg]);
          }
        }
      } else {
        // V transposed: Vt[(b*16+h)*64+s][t]; 4 groups of 4 consecutive t per lane
        const int hh = (col >> 6) & 15, s = col & 63;
        const int bq = bm0 >> 10;
        bf16* vrow = Vtg + ((size_t)(bq * 16 + hh) * 64 + s) * 1024;
        #pragma unroll
        for (int mi = 0; mi < 2; ++mi) {
          const int vbase = (bm0 & 1023) + wr + mi * 32 + 4 * khalf;
          #pragma unroll
          for (int g = 0; g < 4; ++g) {
            bf16x4 vv;
            #pragma unroll
            for (int j = 0; j < 4; ++j) vv[j] = f2bf(acc[mi][ni][g * 4 + j]);
            *(bf16x4*)(vrow + vbase + g * 8) = vv;
          }
        }
      }
    }
  }
}

// ---------------- split-K GEMM, BK=32, 32x32x16 MFMA, bf16 partials ----------------
__global__ __launch_bounds__(256) void gemm_bt_split(const bf16* __restrict__ A,
                                                     const bf16* __restrict__ B,
                                                     bf16* __restrict__ P,
                                                     int M, int N, int Kfull, int Kper) {
  constexpr int BM = 128, BN = 128, BK = 32;
  __shared__ bf16 As[BM * BK];
  __shared__ bf16 Bs[BN * BK];
  const int tid = threadIdx.x;
  const int wave = tid >> 6, lane = tid & 63;
  const int l31 = lane & 31, khalf = lane >> 5;
  const int lin = blockIdx.x + 8 * blockIdx.y;
  const int xcd = lin & 7, idx = lin >> 3;
  const int bm0 = (xcd * 4 + (idx & 3)) * BM;
  const int bn0 = (idx >> 2) * BN;
  const int wr = (wave >> 1) * 64, wc = (wave & 1) * 64;
  const int kbeg = blockIdx.z * Kper;
  const int kend = min(kbeg + Kper, Kfull);
  bf16* Pz = P + (size_t)blockIdx.z * M * N;
  f32x16 acc[2][2] = {};

  for (int k0 = kbeg; k0 < kend; k0 += BK) {
    __syncthreads();
    #pragma unroll
    for (int i = 0; i < 2; ++i) {
      const int id = tid + i * 256;
      const int r = id >> 2, c = swz(r, id & 3) * 8;
      __builtin_amdgcn_global_load_lds(
          (GLOBAL_AS void*)(A + (size_t)(bm0 + r) * Kfull + k0 + c),
          (LDS_AS void*)(As + (size_t)(i * 256 + wave * 64) * 8), 16, 0, 0);
      __builtin_amdgcn_global_load_lds(
          (GLOBAL_AS void*)(B + (size_t)(bn0 + r) * Kfull + k0 + c),
          (LDS_AS void*)(Bs + (size_t)(i * 256 + wave * 64) * 8), 16, 0, 0);
    }
    __syncthreads();
    #pragma unroll
    for (int h = 0; h < 2; ++h) {
      const int c0 = h * 2 + khalf;
      bf16x8 af[2], bfr[2];
      #pragma unroll
      for (int mi = 0; mi < 2; ++mi) {
        const int r = wr + mi * 32 + l31;
        af[mi] = *(const bf16x8*)(As + (r * 4 + swz(r, c0)) * 8);
      }
      #pragma unroll
      for (int ni = 0; ni < 2; ++ni) {
        const int r = wc + ni * 32 + l31;
        bfr[ni] = *(const bf16x8*)(Bs + (r * 4 + swz(r, c0)) * 8);
      }
      #pragma unroll
      for (int mi = 0; mi < 2; ++mi)
        #pragma unroll
        for (int ni = 0; ni < 2; ++ni)
          acc[mi][ni] = __builtin_amdgcn_mfma_f32_32x32x16_bf16(af[mi], bfr[ni], acc[mi][ni], 0, 0, 0);
    }
  }

  #pragma unroll
  for (int ni = 0; ni < 2; ++ni) {
    const int col = bn0 + wc + ni * 32 + l31;
    #pragma unroll
    for (int mi = 0; mi < 2; ++mi) {
      const int rbase = bm0 + wr + mi * 32 + 4 * khalf;
      #pragma unroll
      for (int reg = 0; reg < 16; ++reg) {
        const int row = rbase + (reg & 3) + 8 * (reg >> 2);
        Pz[(size_t)row * N + col] = f2bf(acc[mi][ni][reg]);
      }
    }
  }
}

// ---------------- reduce wo-splits(3, bf16) + residual + LN2 fused ----------------
__global__ __launch_bounds__(256) void reduce_wo_ln(const float* __restrict__ x,
                                                    const bf16* __restrict__ P,
                                                    const float* __restrict__ g,
                                                    const float* __restrict__ b,
                                                    float* __restrict__ y,
                                                    bf16* __restrict__ lnout) {
  constexpr size_t MN = (size_t)4096 * 1024;
  const int row = blockIdx.x, tid = threadIdx.x;
  const size_t base = (size_t)row * 1024;
  const float4 vx = ((const float4*)(x + base))[tid];
  const bf16x4 p0 = ((const bf16x4*)(P + base))[tid];
  const bf16x4 p1 = ((const bf16x4*)(P + base + MN))[tid];
  const bf16x4 p2 = ((const bf16x4*)(P + base + 2 * MN))[tid];
  float4 v;
  v.x = vx.x + (float)p0[0] + (float)p1[0] + (float)p2[0];
  v.y = vx.y + (float)p0[1] + (float)p1[1] + (float)p2[1];
  v.z = vx.z + (float)p0[2] + (float)p1[2] + (float)p2[2];
  v.w = vx.w + (float)p0[3] + (float)p1[3] + (float)p2[3];
  ((float4*)(y + base))[tid] = v;
  float s = v.x + v.y + v.z + v.w;
  float ss = v.x * v.x + v.y * v.y + v.z * v.z + v.w * v.w;
  s = waveSum(s); ss = waveSum(ss);
  __shared__ float rs[4], rq[4];
  if ((tid & 63) == 0) { rs[tid >> 6] = s; rq[tid >> 6] = ss; }
  __syncthreads();
  s = rs[0] + rs[1] + rs[2] + rs[3];
  ss = rq[0] + rq[1] + rq[2] + rq[3];
  const float mu = s * (1.f / 1024.f);
  const float var = ss * (1.f / 1024.f) - mu * mu;
  const float rstd = rsqrtf(var + 1e-5f);
  const float4 gv = ((const float4*)g)[tid];
  const float4 bv = ((const float4*)b)[tid];
  bf16x4 o;
  o[0] = f2bf((v.x - mu) * rstd * gv.x + bv.x);
  o[1] = f2bf((v.y - mu) * rstd * gv.y + bv.y);
  o[2] = f2bf((v.z - mu) * rstd * gv.z + bv.z);
  o[3] = f2bf((v.w - mu) * rstd * gv.w + bv.w);
  ((bf16x4*)(lnout + base))[tid] = o;
}

// ---------------- reduce down-splits(3, bf16) + residual (in-place on y) ----------------
__global__ __launch_bounds__(256) void reduce_down(float* __restrict__ y,
                                                   const bf16* __restrict__ P) {
  constexpr size_t MN = (size_t)4096 * 1024;
  const size_t i = (size_t)blockIdx.x * 256 + threadIdx.x;
  const float4 vy = ((const float4*)y)[i];
  const bf16x4 p0 = ((const bf16x4*)P)[i];
  const bf16x4 p1 = ((const bf16x4*)(P + MN))[i];
  const bf16x4 p2 = ((const bf16x4*)(P + 2 * MN))[i];
  float4 v;
  v.x = vy.x + (float)p0[0] + (float)p1[0] + (float)p2[0];
  v.y = vy.y + (float)p0[1] + (float)p1[1] + (float)p2[1];
  v.z = vy.z + (float)p0[2] + (float)p1[2] + (float)p2[2];
  v.w = vy.w + (float)p0[3] + (float)p1[3] + (float)p2[3];
  ((float4*)y)[i] = v;
}

// ---------------- flash attention: 64-row Q-tile, fixed-shift softmax (R9-proven) ----------------
__global__ __launch_bounds__(256) void attn_flash(const bf16* __restrict__ Qs,
                                                  const bf16* __restrict__ Ks,
                                                  const bf16* __restrict__ Vtg,
                                                  const float* __restrict__ p_scale_ptr,
                                                  bf16* __restrict__ out) {
  constexpr int LDP = 72;
  const int bh = blockIdx.x;
  const int b = bh >> 4, h = bh & 15;
  const int ttile = 15 - (int)blockIdx.y;
  const int t0 = ttile * 64;
  const int tid = threadIdx.x, wave = tid >> 6, lane = tid & 63, quad = lane >> 4, l16 = lane & 15;

  __shared__ bf16 Kst[64 * LDP];
  __shared__ bf16 Vt[64 * LDP];
  __shared__ bf16 Plds[4][16 * LDP];

  const float pscale2 = p_scale_ptr[0] * 1.44269504f;
  const float sc2 = 0.125f * 1.44269504f;

  const bf16* Qb = Qs + ((size_t)bh * 1024 + t0) * 64;
  const bf16* Kb = Ks + ((size_t)bh * 1024) * 64;
  const bf16* Vb = Vtg + ((size_t)bh * 64) * 1024;

  const int trow = wave * 16 + l16;
  const bf16x8 qf0 = *(const bf16x8*)(Qb + trow * 64 + quad * 8);
  const bf16x8 qf1 = *(const bf16x8*)(Qb + trow * 64 + 32 + quad * 8);

  float lsum[4] = {0.f, 0.f, 0.f, 0.f};
  f32x4 Oacc[4] = {};

  bf16x8 st[4];
  auto loadTile = [&](int u0) {
    #pragma unroll
    for (int i = 0; i < 2; ++i) {
      const int cid = tid + i * 256;
      st[i] = *(const bf16x8*)(Kb + (size_t)u0 * 64 + cid * 8);
      st[2 + i] = *(const bf16x8*)(Vb + (size_t)(cid >> 3) * 1024 + u0 + (cid & 7) * 8);
    }
  };
  loadTile(0);

  for (int ut = 0; ut <= ttile; ++ut) {
    const int u0 = ut * 64;
    #pragma unroll
    for (int i = 0; i < 2; ++i) {
      const int cid = tid + i * 256;
      const int r = cid >> 3, c8 = (cid & 7) * 8;
      *(bf16x8*)(Kst + r * LDP + c8) = st[i];
      *(bf16x8*)(Vt + r * LDP + c8) = st[2 + i];
    }
    __syncthreads();
    if (ut < ttile) loadTile(u0 + 64);

    f32x4 sc[4];
    #pragma unroll
    for (int ni = 0; ni < 4; ++ni) {
      const bf16x8 k0 = *(const bf16x8*)(Kst + (ni * 16 + l16) * LDP + quad * 8);
      const bf16x8 k1 = *(const bf16x8*)(Kst + (ni * 16 + l16) * LDP + 32 + quad * 8);
      f32x4 z = {};
      z = __builtin_amdgcn_mfma_f32_16x16x32_bf16(qf0, k0, z, 0, 0, 0);
      z = __builtin_amdgcn_mfma_f32_16x16x32_bf16(qf1, k1, z, 0, 0, 0);
      sc[ni] = z;
    }
    const bool diag = (ut == ttile);
    #pragma unroll
    for (int reg = 0; reg < 4; ++reg) {
      const int t = t0 + wave * 16 + quad * 4 + reg;
      #pragma unroll
      for (int ni = 0; ni < 4; ++ni) {
        const int u = u0 + ni * 16 + l16;
        const int d = t - u;
        float v = sc[ni][reg] * sc2;
        if (diag && d < 0) {
          v = -1e30f;
        } else {
          const float bias = (d == 0) ? 1.0f : (float)__builtin_ctz(d) * 0.0625f;
          v += pscale2 * bias;
        }
        const float p = exp2f(fminf(v, 80.f) - 8.f);
        lsum[reg] += p;
        Plds[wave][(quad * 4 + reg) * LDP + ni * 16 + l16] = f2bf(p);
      }
    }
    const bf16x8 pf0 = *(const bf16x8*)(&Plds[wave][l16 * LDP + quad * 8]);
    const bf16x8 pf1 = *(const bf16x8*)(&Plds[wave][l16 * LDP + 32 + quad * 8]);
    #pragma unroll
    for (int ni = 0; ni < 4; ++ni) {
      const bf16x8 v0 = *(const bf16x8*)(Vt + (ni * 16 + l16) * LDP + quad * 8);
      const bf16x8 v1 = *(const bf16x8*)(Vt + (ni * 16 + l16) * LDP + 32 + quad * 8);
      Oacc[ni] = __builtin_amdgcn_mfma_f32_16x16x32_bf16(pf0, v0, Oacc[ni], 0, 0, 0);
      Oacc[ni] = __builtin_amdgcn_mfma_f32_16x16x32_bf16(pf1, v1, Oacc[ni], 0, 0, 0);
    }
    __syncthreads();
  }

  #pragma unroll
  for (int reg = 0; reg < 4; ++reg) {
    float rs = lsum[reg];
    #pragma unroll
    for (int o = 1; o < 16; o <<= 1) rs += __shfl_xor(rs, o);
    lsum[reg] = 1.0f / rs;
  }

  #pragma unroll
  for (int ni = 0; ni < 4; ++ni)
    #pragma unroll
    for (int reg = 0; reg < 4; ++reg) {
      const int t = t0 + wave * 16 + quad * 4 + reg;
      out[((size_t)(b * 1024 + t)) * 1024 + h * 64 + ni * 16 + l16] = f2bf(Oacc[ni][reg] * lsum[reg]);
    }
}

// ---------------- SO(2) rotation + LN(3072) + SiLU, bf16 in/out ----------------
__global__ __launch_bounds__(256) void rot_ln_silu(const bf16* __restrict__ hb,
                                                   const float* __restrict__ theta,
                                                   const float* __restrict__ g,
                                                   const float* __restrict__ bb,
                                                   bf16* __restrict__ out) {
  const int row = blockIdx.x, tid = threadIdx.x;
  const bf16* hr = hb + (size_t)row * 3072;
  float r[12];
  float s = 0.f, ss = 0.f;
  #pragma unroll
  for (int i = 0; i < 6; ++i) {
    const int p = tid + i * 256;
    const bf16x2 ab = *(const bf16x2*)(hr + 2 * p);
    const float a = (float)ab[0], b_ = (float)ab[1];
    const float th = theta[p];
    const float c = cosf(th), sn = sinf(th);
    const float r0 = c * a - sn * b_;
    const float r1 = sn * a + c * b_;
    r[2 * i] = r0; r[2 * i + 1] = r1;
    s += r0 + r1;
    ss += r0 * r0 + r1 * r1;
  }
  s = waveSum(s); ss = waveSum(ss);
  __shared__ float rs_[4], rq_[4];
  if ((tid & 63) == 0) { rs_[tid >> 6] = s; rq_[tid >> 6] = ss; }
  __syncthreads();
  s = rs_[0] + rs_[1] + rs_[2] + rs_[3];
  ss = rq_[0] + rq_[1] + rq_[2] + rq_[3];
  const float mu = s * (1.f / 3072.f);
  const float var = ss * (1.f / 3072.f) - mu * mu;
  const float rstd = rsqrtf(var + 1e-5f);
  bf16* orow = out + (size_t)row * 3072;
  #pragma unroll
  for (int i = 0; i < 6; ++i) {
    const int p = tid + i * 256;
    const float2 gv = *(const float2*)(g + 2 * p);
    const float2 bv = *(const float2*)(bb + 2 * p);
    const float y0 = (r[2 * i] - mu) * rstd * gv.x + bv.x;
    const float y1 = (r[2 * i + 1] - mu) * rstd * gv.y + bv.y;
    const float o0 = y0 / (1.f + expf(-y0));
    const float o1 = y1 / (1.f + expf(-y1));
    bf16x2 o; o[0] = f2bf(o0); o[1] = f2bf(o1);
    *(bf16x2*)(orow + 2 * p) = o;
  }
}

// ---------------- host launch ----------------
extern "C" void kernel_launch(void* const* d_in, const int* in_sizes, int n_in,
                              void* d_out, int out_size, void* d_ws, size_t ws_size,
                              hipStream_t stream) {
  const float* x    = (const float*)d_in[0];
  const float* wq   = (const float*)d_in[1];
  const float* wk   = (const float*)d_in[2];
  const float* wv   = (const float*)d_in[3];
  const float* wo   = (const float*)d_in[4];
  const float* su   = (const float*)d_in[5];
  const float* sv   = (const float*)d_in[6];
  const float* psc  = (const float*)d_in[7];
  const float* n1g  = (const float*)d_in[8];
  const float* n1b  = (const float*)d_in[9];
  const float* n2g  = (const float*)d_in[10];
  const float* n2b  = (const float*)d_in[11];
  const float* wup  = (const float*)d_in[12];
  const float* wdn  = (const float*)d_in[13];
  const float* th   = (const float*)d_in[14];
  const float* mg   = (const float*)d_in[15];
  const float* mb   = (const float*)d_in[16];
  float* outp = (float*)d_out;

  char* ws = (char*)d_ws;
  size_t off = 0;
  auto alloc = [&](size_t bytes) { size_t o = off; off += (bytes + 255) & ~(size_t)255; return o; };
  constexpr size_t MB84 = (size_t)4096 * 1024 * 2;
  unsigned* amax = (unsigned*)(ws + alloc(32));
  bf16* Su    = (bf16*)(ws + alloc(4096 * 2));
  bf16* Sv    = (bf16*)(ws + alloc(4096 * 2));
  bf16* Wo    = (bf16*)(ws + alloc((size_t)1024 * 1024 * 2));
  bf16* Wup   = (bf16*)(ws + alloc((size_t)3072 * 1024 * 2));
  bf16* Wdn   = (bf16*)(ws + alloc((size_t)1024 * 3072 * 2));
  bf16* Wqkv2 = (bf16*)(ws + alloc((size_t)3072 * 1024 * 2));
  bf16* Wqk   = (bf16*)(ws + alloc((size_t)2048 * 1024 * 2));
  bf16* lnbuf = (bf16*)(ws + alloc(MB84));
  char* arena = ws + alloc(6 * MB84);
  bf16* Qsb   = (bf16*)(arena);
  bf16* Ksb   = (bf16*)(arena + MB84);
  bf16* Vtg   = (bf16*)(arena + 2 * MB84);
  bf16* attno = (bf16*)(arena + 3 * MB84);
  bf16* hbuf  = (bf16*)(arena);
  bf16* gbuf  = (bf16*)(arena + 3 * MB84);
  bf16* Pbuf  = (bf16*)(ws + alloc((size_t)3 * 4096 * 1024 * 2));

  hipMemsetAsync(amax, 0, 32, stream);

  QTasks qt;
  int blk = 0;
  auto add = [&](int i, const float* s, bf16* d, int n) {
    qt.t[i].src = s; qt.t[i].dst = d; qt.t[i].n = n; qt.t[i].slot = i; qt.t[i].blk0 = blk;
    blk += n / 4096;
  };
  add(0, wq, Wqk, 1024 * 1024);
  add(1, wk, Wqk + (size_t)1024 * 1024, 1024 * 1024);
  add(2, wv, Wqkv2 + (size_t)2048 * 1024, 1024 * 1024);
  add(3, wo, Wo, 1024 * 1024);
  add(4, su, Su, 4096);
  add(5, sv, Sv, 4096);
  add(6, wup, Wup, 3072 * 1024);
  add(7, wdn, Wdn, 3072 * 1024);

  absmax_all<<<blk, 256, 0, stream>>>(qt, amax);
  quant_all<<<blk, 256, 0, stream>>>(qt, amax);
  premul_stalk<<<dim3(32, 16), 256, 0, stream>>>(Su, Sv, Wqk, Wqkv2);

  ln_kernel<<<4096, 256, 0, stream>>>(x, n1g, n1b, lnbuf);
  gemm_bt<1><<<dim3(24, 32), 256, 0, stream>>>(lnbuf, Wqkv2, nullptr, Qsb, Ksb, Vtg, 4096, 3072, 1024);
  attn_flash<<<dim3(64, 16), 256, 0, stream>>>(Qsb, Ksb, Vtg, psc, attno);
  gemm_bt_split<<<dim3(8, 32, 3), 256, 0, stream>>>(attno, Wo, Pbuf, 4096, 1024, 1024, 352);
  reduce_wo_ln<<<4096, 256, 0, stream>>>(x, Pbuf, n2g, n2b, outp, lnbuf);
  gemm_bt<0><<<dim3(24, 32), 256, 0, stream>>>(lnbuf, Wup, hbuf, nullptr, nullptr, nullptr, 4096, 3072, 1024);
  rot_ln_silu<<<4096, 256, 0, stream>>>(hbuf, th, mg, mb, gbuf);
  gemm_bt_split<<<dim3(8, 32, 3), 256, 0, stream>>>(gbuf, Wdn, Pbuf, 4096, 1024, 3072, 1024);
  reduce_down<<<4096, 256, 0, stream>>>(outp, Pbuf);
}